// Round 19
// baseline (780.901 us; speedup 1.0000x reference)
//
#include <hip/hip_runtime.h>

#define M_DIM 8192
#define K_DIM 4096
#define N_DIM 16384
#define KT 32   // K tiles of 128 (= one weight scale block)

typedef __attribute__((ext_vector_type(4))) int i32x4;
typedef __attribute__((ext_vector_type(4))) float f32x4;

__device__ __forceinline__ int pack4(int a, int b, int c, int d) {
  return (a & 255) | ((b & 255) << 8) | ((c & 255) << 16) | (d << 24);
}

// ---- pre-pass 1: x fp32 -> int8 per-row, sx[row] = rowmax/127 ------------
__global__ __launch_bounds__(256) void quant_x_kernel(const float* __restrict__ x,
    char* __restrict__ xq, float* __restrict__ sx) {
  const int row = blockIdx.x;
  const int tid = threadIdx.x;
  const float4* xr = reinterpret_cast<const float4*>(x + (size_t)row * K_DIM);
  float4 v[4];
  float m = 0.f;
#pragma unroll
  for (int j = 0; j < 4; ++j) {
    v[j] = xr[tid * 4 + j];
    m = fmaxf(m, fmaxf(fmaxf(fabsf(v[j].x), fabsf(v[j].y)),
                       fmaxf(fabsf(v[j].z), fabsf(v[j].w))));
  }
#pragma unroll
  for (int o = 32; o > 0; o >>= 1) m = fmaxf(m, __shfl_xor(m, o));
  __shared__ float wm[4];
  if ((tid & 63) == 0) wm[tid >> 6] = m;
  __syncthreads();
  m = fmaxf(fmaxf(wm[0], wm[1]), fmaxf(wm[2], wm[3]));
  const float r = (m > 0.f) ? 127.f / m : 0.f;
  i32x4 pk;
#pragma unroll
  for (int j = 0; j < 4; ++j)
    pk[j] = pack4((int)rintf(v[j].x * r), (int)rintf(v[j].y * r),
                  (int)rintf(v[j].z * r), (int)rintf(v[j].w * r));
  reinterpret_cast<i32x4*>(xq + (size_t)row * K_DIM)[tid] = pk;
  if (tid == 0) sx[row] = (m > 0.f) ? m / 127.f : 0.f;
}

// ---- pre-pass 2: w_q int32 -> int8 (exact) -------------------------------
__global__ void repack_w_kernel(const int* __restrict__ wq, char* __restrict__ w8, int n16) {
  int i = blockIdx.x * blockDim.x + threadIdx.x;
  const int stride = gridDim.x * blockDim.x;
  const int4* q = reinterpret_cast<const int4*>(wq);
  i32x4* o = reinterpret_cast<i32x4*>(w8);
  for (; i < n16; i += stride) {
    int4 a = q[4 * i], b = q[4 * i + 1], c = q[4 * i + 2], d = q[4 * i + 3];
    i32x4 r;
    r[0] = pack4(a.x, a.y, a.z, a.w);
    r[1] = pack4(b.x, b.y, b.z, b.w);
    r[2] = pack4(c.x, c.y, c.z, c.w);
    r[3] = pack4(d.x, d.y, d.z, d.w);
    o[i] = r;
  }
}

// ---- async global -> LDS, 16 B per lane ----------------------------------
__device__ __forceinline__ void gload16(const void* g, void* l) {
  __builtin_amdgcn_global_load_lds(
      (const __attribute__((address_space(1))) unsigned int*)g,
      (__attribute__((address_space(3))) unsigned int*)l, 16, 0, 0);
}

#define BAR() do { asm volatile("" ::: "memory"); \
                   __builtin_amdgcn_s_barrier();  \
                   asm volatile("" ::: "memory"); } while (0)

#define MFI(a, b, c) __builtin_amdgcn_mfma_i32_16x16x64_i8(a, b, c, 0, 0, 0)

// ---- 128x128x128 4-wave int8 GEMM, 64x64 waves, single-buf ---------------
// C = sx[row] * (sum_kb ws[nb][kb] * (Aq . Bq^T)_kb) + bias
// r18 verbatim except launch_bounds (256,2)->(256,3): caps regs at ~170
// (demand ~130-140, no spill) while guaranteeing 3 blocks/CU (12 waves).
// r17 (forced 128: 4 blocks + spill) and r18 (heuristic 80: 2.6 blocks +
// residual spill) bracket this point.
__global__ __launch_bounds__(256, 3) void gemm_kernel(
    const char* __restrict__ Aq, const char* __restrict__ Bq,
    const float* __restrict__ ws, const float* __restrict__ sx,
    const float* __restrict__ bias, float* __restrict__ C) {
  // A [128][128B] at 0 (16KB), B [128][128B] at 16384, scales at 32768.
  __shared__ __align__(128) char lds[32768 + 128];

  const int tid = threadIdx.x;
  const int lane = tid & 63, wid = tid >> 6;   // 4 waves
  const int wr = wid >> 1, wc = wid & 1;       // 2x2 wave grid, 64x64/wave

  // Supertile ordering: grid 8192 = 64(tm) x 128(tn) tiles.
  // Super = 16x16 tiles (A 8MB + B 8MB slice, L3-resident).
  const int bid = blockIdx.x;
  const int r = bid & 255;                 // block within super
  const int s = bid >> 8;                  // super id 0..31
  const int sm = s & 3, sn = s >> 2;       // 4 x 8 supers
  const int tm = sm * 16 + (r & 15);       // 0..63
  const int tn = sn * 16 + (r >> 4);       // 0..127

  // stage this block's scale row: ws[tn][0..32)
  if (tid < 32) *(float*)(lds + 32768 + tid * 4) = ws[tn * 32 + tid];

  // staging: per-lane pre-swizzled global source, linear LDS dest
  // one STAGE call = 256 lanes x 16B = 4KB = 32 rows of 128B
  const int srow = tid >> 3;                         // 0..31
  const int kswz = ((tid & 7) ^ (srow & 7)) << 4;    // swizzled byte offset
  const char* aSrc = Aq + (size_t)(tm * 128 + srow) * K_DIM + kswz;
  const char* bSrc = Bq + (size_t)(tn * 128 + srow) * K_DIM + kswz;
  const int ldst = wid << 10;                        // wave-uniform

#define STAGE_A(tt, g) gload16(aSrc + (size_t)(g)*32*K_DIM + (size_t)(tt)*128, \
                               lds + (g)*4096 + ldst)
#define STAGE_B(tt, g) gload16(bSrc + (size_t)(g)*32*K_DIM + (size_t)(tt)*128, \
                               lds + 16384 + (g)*4096 + ldst)
#define STAGE_TILE(tt) do { \
    STAGE_A(tt, 0); STAGE_A(tt, 1); STAGE_A(tt, 2); STAGE_A(tt, 3); \
    STAGE_B(tt, 0); STAGE_B(tt, 1); STAGE_B(tt, 2); STAGE_B(tt, 3); \
  } while (0)

  // fragment addressing (swizzled): 16B unit u stored at u^(row&7); row&7==lane&7
  const int hi = lane >> 4, lo3 = lane & 7;
  const int aks0 = ((0 + hi) ^ lo3) << 4;   // kstep 0 (k 0..63)
  const int aks1 = ((4 + hi) ^ lo3) << 4;   // kstep 1 (k 64..127)
  const int aoff = (wr * 64 + (lane & 15)) * 128;
  const int boff = 16384 + (wc * 64 + (lane & 15)) * 128;

  f32x4 accf[4][4] = {};

  // ---- prologue: stage tile 0 ------------------------------------------
  STAGE_TILE(0);
  asm volatile("s_waitcnt vmcnt(0) lgkmcnt(0)" ::: "memory");  // tile 0 + scales in
  BAR();

  for (int t = 0; t < KT; ++t) {
    const char* Ab = lds + aoff;
    const char* Bb = lds + boff;
    const float csc = *(const float*)(lds + 32768 + (t << 2));

    // ---- B fragments (8 ds_read_b128) ------------------------------------
    i32x4 fb[4][2];
#pragma unroll
    for (int ni = 0; ni < 4; ++ni) {
      fb[ni][0] = *(const i32x4*)(Bb + ni * 2048 + aks0);
      fb[ni][1] = *(const i32x4*)(Bb + ni * 2048 + aks1);
    }

    // ---- per mi-group: 2 A reads, 8 MFMA, immediate rescale --------------
#pragma unroll
    for (int mi = 0; mi < 4; ++mi) {
      const i32x4 fa0 = *(const i32x4*)(Ab + mi * 2048 + aks0);
      const i32x4 fa1 = *(const i32x4*)(Ab + mi * 2048 + aks1);
      i32x4 q0, q1, q2, q3;
      const i32x4 z4 = {0, 0, 0, 0};
      __builtin_amdgcn_s_setprio(1);
      q0 = MFI(fa0, fb[0][0], z4);
      q1 = MFI(fa0, fb[1][0], z4);
      q2 = MFI(fa0, fb[2][0], z4);
      q3 = MFI(fa0, fb[3][0], z4);
      q0 = MFI(fa1, fb[0][1], q0);
      q1 = MFI(fa1, fb[1][1], q1);
      q2 = MFI(fa1, fb[2][1], q2);
      q3 = MFI(fa1, fb[3][1], q3);
      __builtin_amdgcn_s_setprio(0);
#pragma unroll
      for (int e = 0; e < 4; ++e) {
        accf[mi][0][e] += csc * (float)q0[e];
        accf[mi][1][e] += csc * (float)q1[e];
        accf[mi][2][e] += csc * (float)q2[e];
        accf[mi][3][e] += csc * (float)q3[e];
      }
    }

    // ---- single-buffer turnover: all reads retired (lgkm waits precede
    //      the MFMAs above), so after BAR the buffer is dead -> restage ---
    BAR();
    if (t + 1 < KT) {
      STAGE_TILE(t + 1);
      asm volatile("s_waitcnt vmcnt(0)" ::: "memory");  // tile t+1 landed
      BAR();
    }
  }

  // ---- epilogue: C/D layout col=lane&15, row=(lane>>4)*4+reg; NT stores --
  const int crow0 = tm * 128 + wr * 64 + ((lane >> 4) << 2);
  const int ccol0 = tn * 128 + wc * 64 + (lane & 15);
#pragma unroll
  for (int mi = 0; mi < 4; ++mi) {
    float sxv[4];
#pragma unroll
    for (int e = 0; e < 4; ++e) sxv[e] = sx[crow0 + mi * 16 + e];
#pragma unroll
    for (int ni = 0; ni < 4; ++ni) {
      const float bv = bias[ccol0 + ni * 16];
#pragma unroll
      for (int e = 0; e < 4; ++e)
        __builtin_nontemporal_store(
            sxv[e] * accf[mi][ni][e] + bv,
            &C[(size_t)(crow0 + mi * 16 + e) * N_DIM + ccol0 + ni * 16]);
    }
  }
}

extern "C" void kernel_launch(void* const* d_in, const int* in_sizes, int n_in,
                              void* d_out, int out_size, void* d_ws, size_t ws_size,
                              hipStream_t stream) {
  const float* x    = (const float*)d_in[0];
  const int*   wq   = (const int*)d_in[1];
  const float* wsc  = (const float*)d_in[2];
  const float* bias = (const float*)d_in[3];
  float* out = (float*)d_out;

  const size_t xq_bytes = (size_t)M_DIM * K_DIM;        // 32 MB
  const size_t sx_bytes = (size_t)M_DIM * 4;            // 32 KB
  const size_t w8_bytes = (size_t)N_DIM * K_DIM;        // 64 MB
  if (ws_size < xq_bytes + sx_bytes + w8_bytes) return;

  char*  xq  = (char*)d_ws;
  float* sxp = (float*)((char*)d_ws + xq_bytes);
  char*  w8  = (char*)d_ws + xq_bytes + sx_bytes;

  quant_x_kernel<<<M_DIM, 256, 0, stream>>>(x, xq, sxp);
  repack_w_kernel<<<2048, 256, 0, stream>>>(wq, w8, N_DIM * K_DIM / 16);
  gemm_kernel<<<(M_DIM / 128) * (N_DIM / 128), 256, 0, stream>>>(
      xq, w8, wsc, sxp, bias, out);
}

// Round 21
// 762.359 us; speedup vs baseline: 1.0243x; 1.0243x over previous
//
#include <hip/hip_runtime.h>

#define M_DIM 8192
#define K_DIM 4096
#define N_DIM 16384
#define KT 32   // K tiles of 128 (= one weight scale block)

typedef __attribute__((ext_vector_type(4))) int i32x4;
typedef __attribute__((ext_vector_type(4))) float f32x4;

__device__ __forceinline__ int pack4(int a, int b, int c, int d) {
  return (a & 255) | ((b & 255) << 8) | ((c & 255) << 16) | (d << 24);
}

// ---- pre-pass 1: x fp32 -> int8 per-row, sx[row] = rowmax/127 ------------
__global__ __launch_bounds__(256) void quant_x_kernel(const float* __restrict__ x,
    char* __restrict__ xq, float* __restrict__ sx) {
  const int row = blockIdx.x;
  const int tid = threadIdx.x;
  const float4* xr = reinterpret_cast<const float4*>(x + (size_t)row * K_DIM);
  float4 v[4];
  float m = 0.f;
#pragma unroll
  for (int j = 0; j < 4; ++j) {
    v[j] = xr[tid * 4 + j];
    m = fmaxf(m, fmaxf(fmaxf(fabsf(v[j].x), fabsf(v[j].y)),
                       fmaxf(fabsf(v[j].z), fabsf(v[j].w))));
  }
#pragma unroll
  for (int o = 32; o > 0; o >>= 1) m = fmaxf(m, __shfl_xor(m, o));
  __shared__ float wm[4];
  if ((tid & 63) == 0) wm[tid >> 6] = m;
  __syncthreads();
  m = fmaxf(fmaxf(wm[0], wm[1]), fmaxf(wm[2], wm[3]));
  const float r = (m > 0.f) ? 127.f / m : 0.f;
  i32x4 pk;
#pragma unroll
  for (int j = 0; j < 4; ++j)
    pk[j] = pack4((int)rintf(v[j].x * r), (int)rintf(v[j].y * r),
                  (int)rintf(v[j].z * r), (int)rintf(v[j].w * r));
  reinterpret_cast<i32x4*>(xq + (size_t)row * K_DIM)[tid] = pk;
  if (tid == 0) sx[row] = (m > 0.f) ? m / 127.f : 0.f;
}

// ---- pre-pass 2: w_q int32 -> int8 (exact) -------------------------------
__global__ void repack_w_kernel(const int* __restrict__ wq, char* __restrict__ w8, int n16) {
  int i = blockIdx.x * blockDim.x + threadIdx.x;
  const int stride = gridDim.x * blockDim.x;
  const int4* q = reinterpret_cast<const int4*>(wq);
  i32x4* o = reinterpret_cast<i32x4*>(w8);
  for (; i < n16; i += stride) {
    int4 a = q[4 * i], b = q[4 * i + 1], c = q[4 * i + 2], d = q[4 * i + 3];
    i32x4 r;
    r[0] = pack4(a.x, a.y, a.z, a.w);
    r[1] = pack4(b.x, b.y, b.z, b.w);
    r[2] = pack4(c.x, c.y, c.z, c.w);
    r[3] = pack4(d.x, d.y, d.z, d.w);
    o[i] = r;
  }
}

// ---- async global -> LDS, 16 B per lane ----------------------------------
__device__ __forceinline__ void gload16(const void* g, void* l) {
  __builtin_amdgcn_global_load_lds(
      (const __attribute__((address_space(1))) unsigned int*)g,
      (__attribute__((address_space(3))) unsigned int*)l, 16, 0, 0);
}

#define BAR() do { asm volatile("" ::: "memory"); \
                   __builtin_amdgcn_s_barrier();  \
                   asm volatile("" ::: "memory"); } while (0)

#define MFI(a, b, c) __builtin_amdgcn_mfma_i32_16x16x64_i8(a, b, c, 0, 0, 0)

// ---- 128x128x128 4-wave int8 GEMM, 64x64 waves, split-phase single-buf ---
// C = sx[row] * (sum_kb ws[nb][kb] * (Aq . Bq^T)_kb) + bias
// r20's latency-hiding schedule with the cross-wave race FIXED: the LDS
// tile is striped across waves, and vmcnt is per-wave, so every
// vmcnt(N) that guards a cross-wave LDS read must be FOLLOWED by a
// barrier. Protocol per region: reads -> lgkm(0) -> BAR (region dead) ->
// stage -> vmcnt(4) (own prefetch landed) -> BAR (ALL waves' landed) ->
// consume. B(t+1) staged before compute (latency hides under ~1300cy of
// MFMA); A(t+1) staged before next tile's fb phase.
__global__ __launch_bounds__(256, 3) void gemm_kernel(
    const char* __restrict__ Aq, const char* __restrict__ Bq,
    const float* __restrict__ ws, const float* __restrict__ sx,
    const float* __restrict__ bias, float* __restrict__ C) {
  // A [128][128B] at 0 (16KB), B [128][128B] at 16384, scales at 32768.
  __shared__ __align__(128) char lds[32768 + 128];

  const int tid = threadIdx.x;
  const int lane = tid & 63, wid = tid >> 6;   // 4 waves
  const int wr = wid >> 1, wc = wid & 1;       // 2x2 wave grid, 64x64/wave

  // Supertile ordering: grid 8192 = 64(tm) x 128(tn) tiles.
  // Super = 16x16 tiles (A 8MB + B 8MB slice, L3-resident).
  const int bid = blockIdx.x;
  const int r = bid & 255;                 // block within super
  const int s = bid >> 8;                  // super id 0..31
  const int sm = s & 3, sn = s >> 2;       // 4 x 8 supers
  const int tm = sm * 16 + (r & 15);       // 0..63
  const int tn = sn * 16 + (r >> 4);       // 0..127

  // stage this block's scale row: ws[tn][0..32)
  if (tid < 32) *(float*)(lds + 32768 + tid * 4) = ws[tn * 32 + tid];

  // staging: per-lane pre-swizzled global source, linear LDS dest
  // one STAGE call = 256 lanes x 16B = 4KB = 32 rows of 128B
  const int srow = tid >> 3;                         // 0..31
  const int kswz = ((tid & 7) ^ (srow & 7)) << 4;    // swizzled byte offset
  const char* aSrc = Aq + (size_t)(tm * 128 + srow) * K_DIM + kswz;
  const char* bSrc = Bq + (size_t)(tn * 128 + srow) * K_DIM + kswz;
  const int ldst = wid << 10;                        // wave-uniform

#define STAGE_A(tt, g) gload16(aSrc + (size_t)(g)*32*K_DIM + (size_t)(tt)*128, \
                               lds + (g)*4096 + ldst)
#define STAGE_B(tt, g) gload16(bSrc + (size_t)(g)*32*K_DIM + (size_t)(tt)*128, \
                               lds + 16384 + (g)*4096 + ldst)
#define STAGE_A4(tt) do { STAGE_A(tt,0); STAGE_A(tt,1); STAGE_A(tt,2); STAGE_A(tt,3); } while (0)
#define STAGE_B4(tt) do { STAGE_B(tt,0); STAGE_B(tt,1); STAGE_B(tt,2); STAGE_B(tt,3); } while (0)

  // fragment addressing (swizzled): 16B unit u stored at u^(row&7); row&7==lane&7
  const int hi = lane >> 4, lo3 = lane & 7;
  const int aks0 = ((0 + hi) ^ lo3) << 4;   // kstep 0 (k 0..63)
  const int aks1 = ((4 + hi) ^ lo3) << 4;   // kstep 1 (k 64..127)
  const int aoff = (wr * 64 + (lane & 15)) * 128;
  const int boff = 16384 + (wc * 64 + (lane & 15)) * 128;

  f32x4 accf[4][4] = {};

  // ---- prologue: stage tile 0 (B then A: B oldest in the queue) ---------
  STAGE_B4(0);
  STAGE_A4(0);
  asm volatile("s_waitcnt vmcnt(0) lgkmcnt(0)" ::: "memory");  // tile 0 + scales in
  BAR();

  for (int t = 0; t < KT; ++t) {
    const char* Ab = lds + aoff;
    const char* Bb = lds + boff;
    const float csc = *(const float*)(lds + 32768 + (t << 2));

    // ---- phase 1: B fragments (8 ds_read_b128) --------------------------
    i32x4 fb[4][2];
#pragma unroll
    for (int ni = 0; ni < 4; ++ni) {
      fb[ni][0] = *(const i32x4*)(Bb + ni * 2048 + aks0);
      fb[ni][1] = *(const i32x4*)(Bb + ni * 2048 + aks1);
    }
    asm volatile("s_waitcnt lgkmcnt(0)" ::: "memory");  // own fb reads in regs
    BAR();                                              // ALL fb done: B dead
    if (t + 1 < KT) {
      STAGE_B4(t + 1);   // latency hides under the compute phase below
      asm volatile("s_waitcnt vmcnt(4)" ::: "memory");  // own A(t) loads landed
    } else {
      asm volatile("s_waitcnt vmcnt(0)" ::: "memory");
    }
    BAR();               // ALL waves' A(t) slices landed (A is wave-striped!)

    // ---- phase 2: per mi-group 2 A reads, 8 MFMA, immediate rescale -----
#pragma unroll
    for (int mi = 0; mi < 4; ++mi) {
      const i32x4 fa0 = *(const i32x4*)(Ab + mi * 2048 + aks0);
      const i32x4 fa1 = *(const i32x4*)(Ab + mi * 2048 + aks1);
      i32x4 q0, q1, q2, q3;
      const i32x4 z4 = {0, 0, 0, 0};
      __builtin_amdgcn_s_setprio(1);
      q0 = MFI(fa0, fb[0][0], z4);
      q1 = MFI(fa0, fb[1][0], z4);
      q2 = MFI(fa0, fb[2][0], z4);
      q3 = MFI(fa0, fb[3][0], z4);
      q0 = MFI(fa1, fb[0][1], q0);
      q1 = MFI(fa1, fb[1][1], q1);
      q2 = MFI(fa1, fb[2][1], q2);
      q3 = MFI(fa1, fb[3][1], q3);
      __builtin_amdgcn_s_setprio(0);
#pragma unroll
      for (int e = 0; e < 4; ++e) {
        accf[mi][0][e] += csc * (float)q0[e];
        accf[mi][1][e] += csc * (float)q1[e];
        accf[mi][2][e] += csc * (float)q2[e];
        accf[mi][3][e] += csc * (float)q3[e];
      }
    }

    // ---- phase 3: A dead -> stage A(t+1); B(t+1) landed for ALL waves ---
    if (t + 1 < KT) {
      asm volatile("s_waitcnt lgkmcnt(0)" ::: "memory");  // own fa reads retired
      BAR();                                              // ALL fa done: A dead
      STAGE_A4(t + 1);
      asm volatile("s_waitcnt vmcnt(4)" ::: "memory");    // own B(t+1) landed
      BAR();                                              // ALL waves' B(t+1) in
    }
  }

  // ---- epilogue: C/D layout col=lane&15, row=(lane>>4)*4+reg; NT stores --
  const int crow0 = tm * 128 + wr * 64 + ((lane >> 4) << 2);
  const int ccol0 = tn * 128 + wc * 64 + (lane & 15);
#pragma unroll
  for (int mi = 0; mi < 4; ++mi) {
    float sxv[4];
#pragma unroll
    for (int e = 0; e < 4; ++e) sxv[e] = sx[crow0 + mi * 16 + e];
#pragma unroll
    for (int ni = 0; ni < 4; ++ni) {
      const float bv = bias[ccol0 + ni * 16];
#pragma unroll
      for (int e = 0; e < 4; ++e)
        __builtin_nontemporal_store(
            sxv[e] * accf[mi][ni][e] + bv,
            &C[(size_t)(crow0 + mi * 16 + e) * N_DIM + ccol0 + ni * 16]);
    }
  }
}

extern "C" void kernel_launch(void* const* d_in, const int* in_sizes, int n_in,
                              void* d_out, int out_size, void* d_ws, size_t ws_size,
                              hipStream_t stream) {
  const float* x    = (const float*)d_in[0];
  const int*   wq   = (const int*)d_in[1];
  const float* wsc  = (const float*)d_in[2];
  const float* bias = (const float*)d_in[3];
  float* out = (float*)d_out;

  const size_t xq_bytes = (size_t)M_DIM * K_DIM;        // 32 MB
  const size_t sx_bytes = (size_t)M_DIM * 4;            // 32 KB
  const size_t w8_bytes = (size_t)N_DIM * K_DIM;        // 64 MB
  if (ws_size < xq_bytes + sx_bytes + w8_bytes) return;

  char*  xq  = (char*)d_ws;
  float* sxp = (float*)((char*)d_ws + xq_bytes);
  char*  w8  = (char*)d_ws + xq_bytes + sx_bytes;

  quant_x_kernel<<<M_DIM, 256, 0, stream>>>(x, xq, sxp);
  repack_w_kernel<<<2048, 256, 0, stream>>>(wq, w8, N_DIM * K_DIM / 16);
  gemm_kernel<<<(M_DIM / 128) * (N_DIM / 128), 256, 0, stream>>>(
      xq, w8, wsc, sxp, bias, out);
}

// Round 22
// 637.555 us; speedup vs baseline: 1.2248x; 1.1958x over previous
//
#include <hip/hip_runtime.h>

#define M_DIM 8192
#define K_DIM 4096
#define N_DIM 16384
#define KT 32   // K tiles of 128

typedef __attribute__((ext_vector_type(4))) int i32x4;
typedef __attribute__((ext_vector_type(4))) float f32x4;

__device__ __forceinline__ int pack4(int a, int b, int c, int d) {
  return (a & 255) | ((b & 255) << 8) | ((c & 255) << 16) | (d << 24);
}

// ---- pre-pass 1: x fp32 -> int8 per-row, sx[row] = rowmax/127 ------------
__global__ __launch_bounds__(256) void quant_x_kernel(const float* __restrict__ x,
    char* __restrict__ xq, float* __restrict__ sx) {
  const int row = blockIdx.x;
  const int tid = threadIdx.x;
  const float4* xr = reinterpret_cast<const float4*>(x + (size_t)row * K_DIM);
  float4 v[4];
  float m = 0.f;
#pragma unroll
  for (int j = 0; j < 4; ++j) {
    v[j] = xr[tid * 4 + j];
    m = fmaxf(m, fmaxf(fmaxf(fabsf(v[j].x), fabsf(v[j].y)),
                       fmaxf(fabsf(v[j].z), fabsf(v[j].w))));
  }
#pragma unroll
  for (int o = 32; o > 0; o >>= 1) m = fmaxf(m, __shfl_xor(m, o));
  __shared__ float wm[4];
  if ((tid & 63) == 0) wm[tid >> 6] = m;
  __syncthreads();
  m = fmaxf(fmaxf(wm[0], wm[1]), fmaxf(wm[2], wm[3]));
  const float r = (m > 0.f) ? 127.f / m : 0.f;
  i32x4 pk;
#pragma unroll
  for (int j = 0; j < 4; ++j)
    pk[j] = pack4((int)rintf(v[j].x * r), (int)rintf(v[j].y * r),
                  (int)rintf(v[j].z * r), (int)rintf(v[j].w * r));
  reinterpret_cast<i32x4*>(xq + (size_t)row * K_DIM)[tid] = pk;
  if (tid == 0) sx[row] = (m > 0.f) ? m / 127.f : 0.f;
}

// ---- pre-pass 2: w_q * blockscale -> per-ROW int8, sw[row] ---------------
// w8[n,k] = round(w_q[n,k]*ws[nb][kb] / sw[n]), sw[n] = rowmax(|w_q*ws|)/127.
// Makes the GEMM a pure int8 dot over the FULL K (i32 exact, max 66M<2^31).
__global__ __launch_bounds__(256) void requant_w_kernel(const int* __restrict__ wq,
    const float* __restrict__ wsc, char* __restrict__ w8, float* __restrict__ sw) {
  const int row = blockIdx.x;
  const int tid = threadIdx.x;       // covers k = tid*16 .. +16 (one kb each)
  const int4* q = reinterpret_cast<const int4*>(wq + (size_t)row * K_DIM);
  const float s = wsc[(row >> 7) * 32 + (tid >> 3)];   // kb = tid*16/128 = tid/8
  int4 v[4];
  int mx = 0;
#pragma unroll
  for (int j = 0; j < 4; ++j) {
    v[j] = q[tid * 4 + j];
    mx = max(mx, max(max(abs(v[j].x), abs(v[j].y)), max(abs(v[j].z), abs(v[j].w))));
  }
  float fm = s * (float)mx;
#pragma unroll
  for (int o = 32; o > 0; o >>= 1) fm = fmaxf(fm, __shfl_xor(fm, o));
  __shared__ float wmx[4];
  if ((tid & 63) == 0) wmx[tid >> 6] = fm;
  __syncthreads();
  fm = fmaxf(fmaxf(wmx[0], wmx[1]), fmaxf(wmx[2], wmx[3]));
  const float swv = (fm > 0.f) ? fm / 127.f : 0.f;
  const float f = (fm > 0.f) ? s * (127.f / fm) : 0.f;
  if (tid == 0) sw[row] = swv;
  i32x4 pk;
#pragma unroll
  for (int j = 0; j < 4; ++j)
    pk[j] = pack4((int)rintf((float)v[j].x * f), (int)rintf((float)v[j].y * f),
                  (int)rintf((float)v[j].z * f), (int)rintf((float)v[j].w * f));
  reinterpret_cast<i32x4*>(w8 + (size_t)row * K_DIM)[tid] = pk;
}

// ---- async global -> LDS, 16 B per lane ----------------------------------
__device__ __forceinline__ void gload16(const void* g, void* l) {
  __builtin_amdgcn_global_load_lds(
      (const __attribute__((address_space(1))) unsigned int*)g,
      (__attribute__((address_space(3))) unsigned int*)l, 16, 0, 0);
}

#define BAR() do { asm volatile("" ::: "memory"); \
                   __builtin_amdgcn_s_barrier();  \
                   asm volatile("" ::: "memory"); } while (0)

#define MFI(a, b, c) __builtin_amdgcn_mfma_i32_16x16x64_i8(a, b, c, 0, 0, 0)

// ---- 256x256x128 8-wave pure-int8 GEMM (round-1/2 proven structure) ------
// C = sx[row] * sw[col] * (Aq . Bq^T) + bias ; acc i32 exact over K=4096.
// Byte-identical to the verified bf16 256^2 4-phase kernel: 32KB A/B tiles
// (256 rows x 128B), XOR swizzle, same staging + vmcnt(8/4) ledger; only
// the MFMA (16x16x64 i8) and fragment dtype change; KT=32.
__global__ __launch_bounds__(512, 2) void gemm_kernel(
    const char* __restrict__ Aq, const char* __restrict__ Bq,
    const float* __restrict__ sw, const float* __restrict__ sx,
    const float* __restrict__ bias, float* __restrict__ C) {
  __shared__ __align__(128) char lds[131072];  // 2 bufs x (A 32K + B 32K)

  const int tid = threadIdx.x;
  const int lane = tid & 63, wid = tid >> 6;
  const int wr = wid >> 2, wc = wid & 3;    // 2 x 4 wave grid, 128x64/wave

  // Supertile ordering: 2048 blocks = 32(tm) x 64(tn); super = 16x16 tiles
  // (A 8MB + B 8MB int8 slice, L3-resident).
  const int bid = blockIdx.x;
  const int r = bid & 255;
  const int s = bid >> 8;                  // 0..7
  const int sm = s & 1, sn = s >> 1;       // 2 x 4 supers
  const int tm = sm * 16 + (r & 15);       // 0..31
  const int tn = sn * 16 + (r >> 4);       // 0..63

  // staging: per-lane pre-swizzled global source, linear LDS dest
  // one STAGE call = 512 lanes x 16B = 8KB = 64 rows of 128B
  const int srow = (wid << 3) + (lane >> 3);
  const int kswz = ((lane & 7) ^ ((lane >> 3) & 7)) << 4;   // byte offset
  const char* aSrc = Aq + (size_t)(tm * 256 + srow) * K_DIM + kswz;
  const char* bSrc = Bq + (size_t)(tn * 256 + srow) * K_DIM + kswz;
  const int ldst = wid << 10;

#define STAGE_A(tt, h, s2, b) gload16(aSrc + (size_t)((h)*128 + (s2)*64) * K_DIM + (size_t)(tt)*128, \
                                      lds + (b)*65536 + (h)*16384 + (s2)*8192 + ldst)
#define STAGE_B(tt, h, s2, b) gload16(bSrc + (size_t)((h)*128 + (s2)*64) * K_DIM + (size_t)(tt)*128, \
                                      lds + (b)*65536 + 32768 + (h)*16384 + (s2)*8192 + ldst)

  // fragment addressing (swizzled): 16B unit u stored at u^(row&7)
  const int hi = lane >> 4, lo3 = lane & 7;
  const int aks0 = ((0 + hi) ^ lo3) << 4;   // kstep 0 (k 0..63)
  const int aks1 = ((4 + hi) ^ lo3) << 4;   // kstep 1 (k 64..127)
  const int aoff = (wr * 128 + (lane & 15)) * 128;
  const int boff = 32768 + (wc * 64 + (lane & 15)) * 128;

  i32x4 acc[8][4] = {};

  // ---- prologue: stage tiles 0 (buf0) and 1 (buf1) ----------------------
  STAGE_A(0, 0, 0, 0); STAGE_A(0, 0, 1, 0); STAGE_A(0, 1, 0, 0); STAGE_A(0, 1, 1, 0);
  STAGE_B(0, 0, 0, 0); STAGE_B(0, 0, 1, 0); STAGE_B(0, 1, 0, 0); STAGE_B(0, 1, 1, 0);
  STAGE_A(1, 0, 0, 1); STAGE_A(1, 0, 1, 1); STAGE_A(1, 1, 0, 1); STAGE_A(1, 1, 1, 1);
  STAGE_B(1, 0, 0, 1); STAGE_B(1, 0, 1, 1); STAGE_B(1, 1, 0, 1); STAGE_B(1, 1, 1, 1);
  asm volatile("s_waitcnt vmcnt(8)" ::: "memory");  // tile 0 landed; tile 1 in flight
  BAR();

#define AFRAGS(q, P) \
  const i32x4 P##0 = *(const i32x4*)(Ab + (2*(q)    ) * 2048 + aks0); \
  const i32x4 P##1 = *(const i32x4*)(Ab + (2*(q)    ) * 2048 + aks1); \
  const i32x4 P##2 = *(const i32x4*)(Ab + (2*(q) + 1) * 2048 + aks0); \
  const i32x4 P##3 = *(const i32x4*)(Ab + (2*(q) + 1) * 2048 + aks1);

#define QUAD(q, P) \
  __builtin_amdgcn_s_setprio(1); \
  acc[2*(q)][0]   = MFI(P##0, bf00, acc[2*(q)][0]); \
  acc[2*(q)][1]   = MFI(P##0, bf10, acc[2*(q)][1]); \
  acc[2*(q)][2]   = MFI(P##0, bf20, acc[2*(q)][2]); \
  acc[2*(q)][3]   = MFI(P##0, bf30, acc[2*(q)][3]); \
  acc[2*(q)+1][0] = MFI(P##2, bf00, acc[2*(q)+1][0]); \
  acc[2*(q)+1][1] = MFI(P##2, bf10, acc[2*(q)+1][1]); \
  acc[2*(q)+1][2] = MFI(P##2, bf20, acc[2*(q)+1][2]); \
  acc[2*(q)+1][3] = MFI(P##2, bf30, acc[2*(q)+1][3]); \
  acc[2*(q)][0]   = MFI(P##1, bf01, acc[2*(q)][0]); \
  acc[2*(q)][1]   = MFI(P##1, bf11, acc[2*(q)][1]); \
  acc[2*(q)][2]   = MFI(P##1, bf21, acc[2*(q)][2]); \
  acc[2*(q)][3]   = MFI(P##1, bf31, acc[2*(q)][3]); \
  acc[2*(q)+1][0] = MFI(P##3, bf01, acc[2*(q)+1][0]); \
  acc[2*(q)+1][1] = MFI(P##3, bf11, acc[2*(q)+1][1]); \
  acc[2*(q)+1][2] = MFI(P##3, bf21, acc[2*(q)+1][2]); \
  acc[2*(q)+1][3] = MFI(P##3, bf31, acc[2*(q)+1][3]); \
  __builtin_amdgcn_s_setprio(0);

  for (int t = 0; t < KT; ++t) {
    const int p = t & 1, pn = p ^ 1;
    const char* Ab = lds + p * 65536 + aoff;
    const char* Bb = lds + p * 65536 + boff;

    // ---- phase 0: B frags (8) + A quad0 (4); stage A(t+1) half0 ---------
    AFRAGS(0, pa)
    const i32x4 bf00 = *(const i32x4*)(Bb + 0 * 2048 + aks0);
    const i32x4 bf01 = *(const i32x4*)(Bb + 0 * 2048 + aks1);
    const i32x4 bf10 = *(const i32x4*)(Bb + 1 * 2048 + aks0);
    const i32x4 bf11 = *(const i32x4*)(Bb + 1 * 2048 + aks1);
    const i32x4 bf20 = *(const i32x4*)(Bb + 2 * 2048 + aks0);
    const i32x4 bf21 = *(const i32x4*)(Bb + 2 * 2048 + aks1);
    const i32x4 bf30 = *(const i32x4*)(Bb + 3 * 2048 + aks0);
    const i32x4 bf31 = *(const i32x4*)(Bb + 3 * 2048 + aks1);
    if (t > 0 && t + 1 < KT) { STAGE_A(t + 1, 0, 0, pn); STAGE_A(t + 1, 0, 1, pn); }
    BAR();
    QUAD(0, pa)
    BAR();

    // ---- phase 1 --------------------------------------------------------
    AFRAGS(1, pb)
    if (t > 0 && t + 1 < KT) { STAGE_A(t + 1, 1, 0, pn); STAGE_A(t + 1, 1, 1, pn); }
    BAR();
    QUAD(1, pb)
    BAR();

    // ---- phase 2 --------------------------------------------------------
    AFRAGS(2, pc)
    if (t + 2 < KT) { STAGE_B(t + 2, 0, 0, p); STAGE_B(t + 2, 0, 1, p); }
    BAR();
    QUAD(2, pc)
    BAR();

    // ---- phase 3: counted vmcnt -----------------------------------------
    AFRAGS(3, pd)
    if (t + 2 < KT) { STAGE_B(t + 2, 1, 0, p); STAGE_B(t + 2, 1, 1, p); }
    if (t < KT - 2)       asm volatile("s_waitcnt vmcnt(4)" ::: "memory");
    else if (t == KT - 2) asm volatile("s_waitcnt vmcnt(0)" ::: "memory");
    BAR();
    QUAD(3, pd)
    BAR();
  }

  // ---- epilogue: C = sx[row]*sw[col]*acc + bias; NT stores ---------------
  const int crow0 = tm * 256 + wr * 128 + ((lane >> 4) << 2);
  const int ccol0 = tn * 256 + wc * 64 + (lane & 15);
#pragma unroll
  for (int ni = 0; ni < 4; ++ni) {
    const float bv = bias[ccol0 + ni * 16];
    const float swc = sw[ccol0 + ni * 16];
#pragma unroll
    for (int mi = 0; mi < 8; ++mi) {
#pragma unroll
      for (int e = 0; e < 4; ++e) {
        const int row = crow0 + mi * 16 + e;
        __builtin_nontemporal_store(
            sx[row] * swc * (float)acc[mi][ni][e] + bv,
            &C[(size_t)row * N_DIM + ccol0 + ni * 16]);
      }
    }
  }
}

extern "C" void kernel_launch(void* const* d_in, const int* in_sizes, int n_in,
                              void* d_out, int out_size, void* d_ws, size_t ws_size,
                              hipStream_t stream) {
  const float* x    = (const float*)d_in[0];
  const int*   wq   = (const int*)d_in[1];
  const float* wsc  = (const float*)d_in[2];
  const float* bias = (const float*)d_in[3];
  float* out = (float*)d_out;

  const size_t xq_bytes = (size_t)M_DIM * K_DIM;        // 32 MB
  const size_t sx_bytes = (size_t)M_DIM * 4;            // 32 KB
  const size_t w8_bytes = (size_t)N_DIM * K_DIM;        // 64 MB
  const size_t sw_bytes = (size_t)N_DIM * 4;            // 64 KB
  if (ws_size < xq_bytes + sx_bytes + w8_bytes + sw_bytes) return;

  char*  xq  = (char*)d_ws;
  float* sxp = (float*)((char*)d_ws + xq_bytes);
  char*  w8  = (char*)d_ws + xq_bytes + sx_bytes;
  float* swp = (float*)((char*)d_ws + xq_bytes + sx_bytes + w8_bytes);

  quant_x_kernel<<<M_DIM, 256, 0, stream>>>(x, xq, sxp);
  requant_w_kernel<<<N_DIM, 256, 0, stream>>>(wq, wsc, w8, swp);
  gemm_kernel<<<(M_DIM / 256) * (N_DIM / 256), 512, 0, stream>>>(
      xq, w8, swp, sxp, bias, out);
}

// Round 23
// 609.738 us; speedup vs baseline: 1.2807x; 1.0456x over previous
//
#include <hip/hip_runtime.h>

#define M_DIM 8192
#define K_DIM 4096
#define N_DIM 16384
#define KT 32   // K tiles of 128

typedef __attribute__((ext_vector_type(4))) int i32x4;

__device__ __forceinline__ int pack4(int a, int b, int c, int d) {
  return (a & 255) | ((b & 255) << 8) | ((c & 255) << 16) | (d << 24);
}

// ---- pre-pass 1: x fp32 -> int8 per-row, sx[row] = rowmax/127 ------------
__global__ __launch_bounds__(256) void quant_x_kernel(const float* __restrict__ x,
    char* __restrict__ xq, float* __restrict__ sx) {
  const int row = blockIdx.x;
  const int tid = threadIdx.x;
  const float4* xr = reinterpret_cast<const float4*>(x + (size_t)row * K_DIM);
  float4 v[4];
  float m = 0.f;
#pragma unroll
  for (int j = 0; j < 4; ++j) {
    v[j] = xr[tid * 4 + j];
    m = fmaxf(m, fmaxf(fmaxf(fabsf(v[j].x), fabsf(v[j].y)),
                       fmaxf(fabsf(v[j].z), fabsf(v[j].w))));
  }
#pragma unroll
  for (int o = 32; o > 0; o >>= 1) m = fmaxf(m, __shfl_xor(m, o));
  __shared__ float wm[4];
  if ((tid & 63) == 0) wm[tid >> 6] = m;
  __syncthreads();
  m = fmaxf(fmaxf(wm[0], wm[1]), fmaxf(wm[2], wm[3]));
  const float r = (m > 0.f) ? 127.f / m : 0.f;
  i32x4 pk;
#pragma unroll
  for (int j = 0; j < 4; ++j)
    pk[j] = pack4((int)rintf(v[j].x * r), (int)rintf(v[j].y * r),
                  (int)rintf(v[j].z * r), (int)rintf(v[j].w * r));
  reinterpret_cast<i32x4*>(xq + (size_t)row * K_DIM)[tid] = pk;
  if (tid == 0) sx[row] = (m > 0.f) ? m / 127.f : 0.f;
}

// ---- pre-pass 2: w_q * blockscale -> per-ROW int8, sw[row] ---------------
__global__ __launch_bounds__(256) void requant_w_kernel(const int* __restrict__ wq,
    const float* __restrict__ wsc, char* __restrict__ w8, float* __restrict__ sw) {
  const int row = blockIdx.x;
  const int tid = threadIdx.x;
  const int4* q = reinterpret_cast<const int4*>(wq + (size_t)row * K_DIM);
  const float s = wsc[(row >> 7) * 32 + (tid >> 3)];
  int4 v[4];
  int mx = 0;
#pragma unroll
  for (int j = 0; j < 4; ++j) {
    v[j] = q[tid * 4 + j];
    mx = max(mx, max(max(abs(v[j].x), abs(v[j].y)), max(abs(v[j].z), abs(v[j].w))));
  }
  float fm = s * (float)mx;
#pragma unroll
  for (int o = 32; o > 0; o >>= 1) fm = fmaxf(fm, __shfl_xor(fm, o));
  __shared__ float wmx[4];
  if ((tid & 63) == 0) wmx[tid >> 6] = fm;
  __syncthreads();
  fm = fmaxf(fmaxf(wmx[0], wmx[1]), fmaxf(wmx[2], wmx[3]));
  const float swv = (fm > 0.f) ? fm / 127.f : 0.f;
  const float f = (fm > 0.f) ? s * (127.f / fm) : 0.f;
  if (tid == 0) sw[row] = swv;
  i32x4 pk;
#pragma unroll
  for (int j = 0; j < 4; ++j)
    pk[j] = pack4((int)rintf((float)v[j].x * f), (int)rintf((float)v[j].y * f),
                  (int)rintf((float)v[j].z * f), (int)rintf((float)v[j].w * f));
  reinterpret_cast<i32x4*>(w8 + (size_t)row * K_DIM)[tid] = pk;
}

// ---- async global -> LDS, 16 B per lane ----------------------------------
__device__ __forceinline__ void gload16(const void* g, void* l) {
  __builtin_amdgcn_global_load_lds(
      (const __attribute__((address_space(1))) unsigned int*)g,
      (__attribute__((address_space(3))) unsigned int*)l, 16, 0, 0);
}

#define BAR() do { asm volatile("" ::: "memory"); \
                   __builtin_amdgcn_s_barrier();  \
                   asm volatile("" ::: "memory"); } while (0)

#define MFI(a, b, c) __builtin_amdgcn_mfma_i32_16x16x64_i8(a, b, c, 0, 0, 0)

// ---- 256x256x128 8-wave pure-int8 GEMM, 2-barriers-per-tile --------------
// C = sx[row] * sw[col] * (Aq . Bq^T) + bias ; acc i32 exact over K=4096.
// r22 with the 8-barrier 4-phase lockstep collapsed to 2 barriers/tile so
// waves de-phase and LDS-read service overlaps MFMA bursts.
// Ledger per tile t (buf p = t&1): top: STAGE A(t+1)->pn (pn A dead since
// end-BAR of t-1). Mid-BAR after quads 0-1 (all B-frag reads retired) ->
// STAGE B(t+2)->p. End: vmcnt(4) drains {B(t+1), A(t+1)}, leaves B(t+2);
// BAR. Prologue: B0,A0,B1 + vmcnt(4). Tail: vmcnt(0) at KT-2.
__global__ __launch_bounds__(512, 2) void gemm_kernel(
    const char* __restrict__ Aq, const char* __restrict__ Bq,
    const float* __restrict__ sw, const float* __restrict__ sx,
    const float* __restrict__ bias, float* __restrict__ C) {
  __shared__ __align__(128) char lds[131072];  // 2 bufs x (A 32K + B 32K)

  const int tid = threadIdx.x;
  const int lane = tid & 63, wid = tid >> 6;
  const int wr = wid >> 2, wc = wid & 3;    // 2 x 4 wave grid, 128x64/wave

  // Supertile ordering: 2048 blocks = 32(tm) x 64(tn); super = 16x16 tiles.
  const int bid = blockIdx.x;
  const int r = bid & 255;
  const int s = bid >> 8;                  // 0..7
  const int sm = s & 1, sn = s >> 1;       // 2 x 4 supers
  const int tm = sm * 16 + (r & 15);       // 0..31
  const int tn = sn * 16 + (r >> 4);       // 0..63

  // staging: per-lane pre-swizzled global source, linear LDS dest
  const int srow = (wid << 3) + (lane >> 3);
  const int kswz = ((lane & 7) ^ ((lane >> 3) & 7)) << 4;
  const char* aSrc = Aq + (size_t)(tm * 256 + srow) * K_DIM + kswz;
  const char* bSrc = Bq + (size_t)(tn * 256 + srow) * K_DIM + kswz;
  const int ldst = wid << 10;

#define STAGE_A(tt, h, s2, b) gload16(aSrc + (size_t)((h)*128 + (s2)*64) * K_DIM + (size_t)(tt)*128, \
                                      lds + (b)*65536 + (h)*16384 + (s2)*8192 + ldst)
#define STAGE_B(tt, h, s2, b) gload16(bSrc + (size_t)((h)*128 + (s2)*64) * K_DIM + (size_t)(tt)*128, \
                                      lds + (b)*65536 + 32768 + (h)*16384 + (s2)*8192 + ldst)
#define STAGE_A4(tt, b) do { STAGE_A(tt,0,0,b); STAGE_A(tt,0,1,b); STAGE_A(tt,1,0,b); STAGE_A(tt,1,1,b); } while (0)
#define STAGE_B4(tt, b) do { STAGE_B(tt,0,0,b); STAGE_B(tt,0,1,b); STAGE_B(tt,1,0,b); STAGE_B(tt,1,1,b); } while (0)

  // fragment addressing (swizzled): 16B unit u stored at u^(row&7)
  const int hi = lane >> 4, lo3 = lane & 7;
  const int aks0 = ((0 + hi) ^ lo3) << 4;
  const int aks1 = ((4 + hi) ^ lo3) << 4;
  const int aoff = (wr * 128 + (lane & 15)) * 128;
  const int boff = 32768 + (wc * 64 + (lane & 15)) * 128;

  i32x4 acc[8][4] = {};

  // ---- prologue: B0,A0 -> buf0; B1 -> buf1 -------------------------------
  STAGE_B4(0, 0);
  STAGE_A4(0, 0);
  STAGE_B4(1, 1);
  asm volatile("s_waitcnt vmcnt(4)" ::: "memory");  // tile 0 landed; B1 in flight
  BAR();

#define AFRAGS(q, P) \
  const i32x4 P##0 = *(const i32x4*)(Ab + (2*(q)    ) * 2048 + aks0); \
  const i32x4 P##1 = *(const i32x4*)(Ab + (2*(q)    ) * 2048 + aks1); \
  const i32x4 P##2 = *(const i32x4*)(Ab + (2*(q) + 1) * 2048 + aks0); \
  const i32x4 P##3 = *(const i32x4*)(Ab + (2*(q) + 1) * 2048 + aks1);

#define QUAD(q, P) \
  __builtin_amdgcn_s_setprio(1); \
  acc[2*(q)][0]   = MFI(P##0, bf00, acc[2*(q)][0]); \
  acc[2*(q)][1]   = MFI(P##0, bf10, acc[2*(q)][1]); \
  acc[2*(q)][2]   = MFI(P##0, bf20, acc[2*(q)][2]); \
  acc[2*(q)][3]   = MFI(P##0, bf30, acc[2*(q)][3]); \
  acc[2*(q)+1][0] = MFI(P##2, bf00, acc[2*(q)+1][0]); \
  acc[2*(q)+1][1] = MFI(P##2, bf10, acc[2*(q)+1][1]); \
  acc[2*(q)+1][2] = MFI(P##2, bf20, acc[2*(q)+1][2]); \
  acc[2*(q)+1][3] = MFI(P##2, bf30, acc[2*(q)+1][3]); \
  acc[2*(q)][0]   = MFI(P##1, bf01, acc[2*(q)][0]); \
  acc[2*(q)][1]   = MFI(P##1, bf11, acc[2*(q)][1]); \
  acc[2*(q)][2]   = MFI(P##1, bf21, acc[2*(q)][2]); \
  acc[2*(q)][3]   = MFI(P##1, bf31, acc[2*(q)][3]); \
  acc[2*(q)+1][0] = MFI(P##3, bf01, acc[2*(q)+1][0]); \
  acc[2*(q)+1][1] = MFI(P##3, bf11, acc[2*(q)+1][1]); \
  acc[2*(q)+1][2] = MFI(P##3, bf21, acc[2*(q)+1][2]); \
  acc[2*(q)+1][3] = MFI(P##3, bf31, acc[2*(q)+1][3]); \
  __builtin_amdgcn_s_setprio(0);

  for (int t = 0; t < KT; ++t) {
    const int p = t & 1, pn = p ^ 1;
    const char* Ab = lds + p * 65536 + aoff;
    const char* Bb = lds + p * 65536 + boff;

    // top: stage next tile's A into pn (pn A-region dead since t-1's end BAR)
    if (t + 1 < KT) STAGE_A4(t + 1, pn);

    // B fragments for this tile (8 ds_read_b128)
    const i32x4 bf00 = *(const i32x4*)(Bb + 0 * 2048 + aks0);
    const i32x4 bf01 = *(const i32x4*)(Bb + 0 * 2048 + aks1);
    const i32x4 bf10 = *(const i32x4*)(Bb + 1 * 2048 + aks0);
    const i32x4 bf11 = *(const i32x4*)(Bb + 1 * 2048 + aks1);
    const i32x4 bf20 = *(const i32x4*)(Bb + 2 * 2048 + aks0);
    const i32x4 bf21 = *(const i32x4*)(Bb + 2 * 2048 + aks1);
    const i32x4 bf30 = *(const i32x4*)(Bb + 3 * 2048 + aks0);
    const i32x4 bf31 = *(const i32x4*)(Bb + 3 * 2048 + aks1);

    // quads 0-1 (A reads inline; consumption retires all B reads)
    {
      AFRAGS(0, pa)
      QUAD(0, pa)
      AFRAGS(1, pb)
      QUAD(1, pb)
    }
    BAR();   // all waves' B-frag (and quad0/1 A) reads retired: B region dead
    if (t + 2 < KT) STAGE_B4(t + 2, p);

    // quads 2-3
    {
      AFRAGS(2, pc)
      QUAD(2, pc)
      AFRAGS(3, pd)
      QUAD(3, pd)
    }

    // end: drain {B(t+1), A(t+1)}; leave B(t+2) in flight
    if (t < KT - 2)       asm volatile("s_waitcnt vmcnt(4)" ::: "memory");
    else if (t == KT - 2) asm volatile("s_waitcnt vmcnt(0)" ::: "memory");
    if (t + 1 < KT) BAR();
  }

  // ---- epilogue: C = sx[row]*sw[col]*acc + bias; NT stores ---------------
  const int crow0 = tm * 256 + wr * 128 + ((lane >> 4) << 2);
  const int ccol0 = tn * 256 + wc * 64 + (lane & 15);
#pragma unroll
  for (int ni = 0; ni < 4; ++ni) {
    const float bv = bias[ccol0 + ni * 16];
    const float swc = sw[ccol0 + ni * 16];
#pragma unroll
    for (int mi = 0; mi < 8; ++mi) {
#pragma unroll
      for (int e = 0; e < 4; ++e) {
        const int row = crow0 + mi * 16 + e;
        __builtin_nontemporal_store(
            sx[row] * swc * (float)acc[mi][ni][e] + bv,
            &C[(size_t)row * N_DIM + ccol0 + ni * 16]);
      }
    }
  }
}

extern "C" void kernel_launch(void* const* d_in, const int* in_sizes, int n_in,
                              void* d_out, int out_size, void* d_ws, size_t ws_size,
                              hipStream_t stream) {
  const float* x    = (const float*)d_in[0];
  const int*   wq   = (const int*)d_in[1];
  const float* wsc  = (const float*)d_in[2];
  const float* bias = (const float*)d_in[3];
  float* out = (float*)d_out;

  const size_t xq_bytes = (size_t)M_DIM * K_DIM;        // 32 MB
  const size_t sx_bytes = (size_t)M_DIM * 4;            // 32 KB
  const size_t w8_bytes = (size_t)N_DIM * K_DIM;        // 64 MB
  const size_t sw_bytes = (size_t)N_DIM * 4;            // 64 KB
  if (ws_size < xq_bytes + sx_bytes + w8_bytes + sw_bytes) return;

  char*  xq  = (char*)d_ws;
  float* sxp = (float*)((char*)d_ws + xq_bytes);
  char*  w8  = (char*)d_ws + xq_bytes + sx_bytes;
  float* swp = (float*)((char*)d_ws + xq_bytes + sx_bytes + w8_bytes);

  quant_x_kernel<<<M_DIM, 256, 0, stream>>>(x, xq, sxp);
  requant_w_kernel<<<N_DIM, 256, 0, stream>>>(wq, wsc, w8, swp);
  gemm_kernel<<<(M_DIM / 256) * (N_DIM / 256), 512, 0, stream>>>(
      xq, w8, swp, sxp, bias, out);
}

// Round 24
// 602.939 us; speedup vs baseline: 1.2952x; 1.0113x over previous
//
#include <hip/hip_runtime.h>

#define M_DIM 8192
#define K_DIM 4096
#define N_DIM 16384
#define KT 32   // K tiles of 128

typedef __attribute__((ext_vector_type(4))) int i32x4;

__device__ __forceinline__ int pack4(int a, int b, int c, int d) {
  return (a & 255) | ((b & 255) << 8) | ((c & 255) << 16) | (d << 24);
}

// ---- pre-pass 1: x fp32 -> int8 per-row, sx[row] = rowmax/127 ------------
__global__ __launch_bounds__(256) void quant_x_kernel(const float* __restrict__ x,
    char* __restrict__ xq, float* __restrict__ sx) {
  const int row = blockIdx.x;
  const int tid = threadIdx.x;
  const float4* xr = reinterpret_cast<const float4*>(x + (size_t)row * K_DIM);
  float4 v[4];
  float m = 0.f;
#pragma unroll
  for (int j = 0; j < 4; ++j) {
    v[j] = xr[tid * 4 + j];
    m = fmaxf(m, fmaxf(fmaxf(fabsf(v[j].x), fabsf(v[j].y)),
                       fmaxf(fabsf(v[j].z), fabsf(v[j].w))));
  }
#pragma unroll
  for (int o = 32; o > 0; o >>= 1) m = fmaxf(m, __shfl_xor(m, o));
  __shared__ float wm[4];
  if ((tid & 63) == 0) wm[tid >> 6] = m;
  __syncthreads();
  m = fmaxf(fmaxf(wm[0], wm[1]), fmaxf(wm[2], wm[3]));
  const float r = (m > 0.f) ? 127.f / m : 0.f;
  i32x4 pk;
#pragma unroll
  for (int j = 0; j < 4; ++j)
    pk[j] = pack4((int)rintf(v[j].x * r), (int)rintf(v[j].y * r),
                  (int)rintf(v[j].z * r), (int)rintf(v[j].w * r));
  reinterpret_cast<i32x4*>(xq + (size_t)row * K_DIM)[tid] = pk;
  if (tid == 0) sx[row] = (m > 0.f) ? m / 127.f : 0.f;
}

// ---- pre-pass 2: w_q * blockscale -> per-ROW int8, sw[row] ---------------
__global__ __launch_bounds__(256) void requant_w_kernel(const int* __restrict__ wq,
    const float* __restrict__ wsc, char* __restrict__ w8, float* __restrict__ sw) {
  const int row = blockIdx.x;
  const int tid = threadIdx.x;
  const int4* q = reinterpret_cast<const int4*>(wq + (size_t)row * K_DIM);
  const float s = wsc[(row >> 7) * 32 + (tid >> 3)];
  int4 v[4];
  int mx = 0;
#pragma unroll
  for (int j = 0; j < 4; ++j) {
    v[j] = q[tid * 4 + j];
    mx = max(mx, max(max(abs(v[j].x), abs(v[j].y)), max(abs(v[j].z), abs(v[j].w))));
  }
  float fm = s * (float)mx;
#pragma unroll
  for (int o = 32; o > 0; o >>= 1) fm = fmaxf(fm, __shfl_xor(fm, o));
  __shared__ float wmx[4];
  if ((tid & 63) == 0) wmx[tid >> 6] = fm;
  __syncthreads();
  fm = fmaxf(fmaxf(wmx[0], wmx[1]), fmaxf(wmx[2], wmx[3]));
  const float swv = (fm > 0.f) ? fm / 127.f : 0.f;
  const float f = (fm > 0.f) ? s * (127.f / fm) : 0.f;
  if (tid == 0) sw[row] = swv;
  i32x4 pk;
#pragma unroll
  for (int j = 0; j < 4; ++j)
    pk[j] = pack4((int)rintf((float)v[j].x * f), (int)rintf((float)v[j].y * f),
                  (int)rintf((float)v[j].z * f), (int)rintf((float)v[j].w * f));
  reinterpret_cast<i32x4*>(w8 + (size_t)row * K_DIM)[tid] = pk;
}

// ---- async global -> LDS, 16 B per lane ----------------------------------
__device__ __forceinline__ void gload16(const void* g, void* l) {
  __builtin_amdgcn_global_load_lds(
      (const __attribute__((address_space(1))) unsigned int*)g,
      (__attribute__((address_space(3))) unsigned int*)l, 16, 0, 0);
}

#define BAR() do { asm volatile("" ::: "memory"); \
                   __builtin_amdgcn_s_barrier();  \
                   asm volatile("" ::: "memory"); } while (0)

#define MFI(a, b, c) __builtin_amdgcn_mfma_i32_16x16x64_i8(a, b, c, 0, 0, 0)

// ---- 256x256x128 8-wave pure-int8 GEMM, 2-barriers-per-tile, NO setprio --
// C = sx[row] * sw[col] * (Aq . Bq^T) + bias ; acc i32 exact over K=4096.
// r23 with the s_setprio pairs REMOVED: the setprio intrinsic is a compiler
// scheduling fence (side-effecting), which forced [read-lump -> MFMA-lump]
// serialization per quad (measured: tile time = LDS + MFMA sum, zero
// overlap). Without it the scheduler interleaves quad q+1's ds_reads under
// quad q's MFMA burst with counted lgkmcnt (matches m190/m141 guidance:
// setprio is role-split-only; order-pinning defeats the scheduler).
__global__ __launch_bounds__(512, 2) void gemm_kernel(
    const char* __restrict__ Aq, const char* __restrict__ Bq,
    const float* __restrict__ sw, const float* __restrict__ sx,
    const float* __restrict__ bias, float* __restrict__ C) {
  __shared__ __align__(128) char lds[131072];  // 2 bufs x (A 32K + B 32K)

  const int tid = threadIdx.x;
  const int lane = tid & 63, wid = tid >> 6;
  const int wr = wid >> 2, wc = wid & 3;    // 2 x 4 wave grid, 128x64/wave

  // Supertile ordering: 2048 blocks = 32(tm) x 64(tn); super = 16x16 tiles.
  const int bid = blockIdx.x;
  const int r = bid & 255;
  const int s = bid >> 8;                  // 0..7
  const int sm = s & 1, sn = s >> 1;       // 2 x 4 supers
  const int tm = sm * 16 + (r & 15);       // 0..31
  const int tn = sn * 16 + (r >> 4);       // 0..63

  // staging: per-lane pre-swizzled global source, linear LDS dest
  const int srow = (wid << 3) + (lane >> 3);
  const int kswz = ((lane & 7) ^ ((lane >> 3) & 7)) << 4;
  const char* aSrc = Aq + (size_t)(tm * 256 + srow) * K_DIM + kswz;
  const char* bSrc = Bq + (size_t)(tn * 256 + srow) * K_DIM + kswz;
  const int ldst = wid << 10;

#define STAGE_A(tt, h, s2, b) gload16(aSrc + (size_t)((h)*128 + (s2)*64) * K_DIM + (size_t)(tt)*128, \
                                      lds + (b)*65536 + (h)*16384 + (s2)*8192 + ldst)
#define STAGE_B(tt, h, s2, b) gload16(bSrc + (size_t)((h)*128 + (s2)*64) * K_DIM + (size_t)(tt)*128, \
                                      lds + (b)*65536 + 32768 + (h)*16384 + (s2)*8192 + ldst)
#define STAGE_A4(tt, b) do { STAGE_A(tt,0,0,b); STAGE_A(tt,0,1,b); STAGE_A(tt,1,0,b); STAGE_A(tt,1,1,b); } while (0)
#define STAGE_B4(tt, b) do { STAGE_B(tt,0,0,b); STAGE_B(tt,0,1,b); STAGE_B(tt,1,0,b); STAGE_B(tt,1,1,b); } while (0)

  // fragment addressing (swizzled): 16B unit u stored at u^(row&7)
  const int hi = lane >> 4, lo3 = lane & 7;
  const int aks0 = ((0 + hi) ^ lo3) << 4;
  const int aks1 = ((4 + hi) ^ lo3) << 4;
  const int aoff = (wr * 128 + (lane & 15)) * 128;
  const int boff = 32768 + (wc * 64 + (lane & 15)) * 128;

  i32x4 acc[8][4] = {};

  // ---- prologue: B0,A0 -> buf0; B1 -> buf1 -------------------------------
  STAGE_B4(0, 0);
  STAGE_A4(0, 0);
  STAGE_B4(1, 1);
  asm volatile("s_waitcnt vmcnt(4)" ::: "memory");  // tile 0 landed; B1 in flight
  BAR();

#define AFRAGS(q, P) \
  const i32x4 P##0 = *(const i32x4*)(Ab + (2*(q)    ) * 2048 + aks0); \
  const i32x4 P##1 = *(const i32x4*)(Ab + (2*(q)    ) * 2048 + aks1); \
  const i32x4 P##2 = *(const i32x4*)(Ab + (2*(q) + 1) * 2048 + aks0); \
  const i32x4 P##3 = *(const i32x4*)(Ab + (2*(q) + 1) * 2048 + aks1);

#define QUAD(q, P) \
  acc[2*(q)][0]   = MFI(P##0, bf00, acc[2*(q)][0]); \
  acc[2*(q)][1]   = MFI(P##0, bf10, acc[2*(q)][1]); \
  acc[2*(q)][2]   = MFI(P##0, bf20, acc[2*(q)][2]); \
  acc[2*(q)][3]   = MFI(P##0, bf30, acc[2*(q)][3]); \
  acc[2*(q)+1][0] = MFI(P##2, bf00, acc[2*(q)+1][0]); \
  acc[2*(q)+1][1] = MFI(P##2, bf10, acc[2*(q)+1][1]); \
  acc[2*(q)+1][2] = MFI(P##2, bf20, acc[2*(q)+1][2]); \
  acc[2*(q)+1][3] = MFI(P##2, bf30, acc[2*(q)+1][3]); \
  acc[2*(q)][0]   = MFI(P##1, bf01, acc[2*(q)][0]); \
  acc[2*(q)][1]   = MFI(P##1, bf11, acc[2*(q)][1]); \
  acc[2*(q)][2]   = MFI(P##1, bf21, acc[2*(q)][2]); \
  acc[2*(q)][3]   = MFI(P##1, bf31, acc[2*(q)][3]); \
  acc[2*(q)+1][0] = MFI(P##3, bf01, acc[2*(q)+1][0]); \
  acc[2*(q)+1][1] = MFI(P##3, bf11, acc[2*(q)+1][1]); \
  acc[2*(q)+1][2] = MFI(P##3, bf21, acc[2*(q)+1][2]); \
  acc[2*(q)+1][3] = MFI(P##3, bf31, acc[2*(q)+1][3]);

  for (int t = 0; t < KT; ++t) {
    const int p = t & 1, pn = p ^ 1;
    const char* Ab = lds + p * 65536 + aoff;
    const char* Bb = lds + p * 65536 + boff;

    // top: stage next tile's A into pn (pn A-region dead since t-1's end BAR)
    if (t + 1 < KT) STAGE_A4(t + 1, pn);

    // B fragments for this tile (8 ds_read_b128)
    const i32x4 bf00 = *(const i32x4*)(Bb + 0 * 2048 + aks0);
    const i32x4 bf01 = *(const i32x4*)(Bb + 0 * 2048 + aks1);
    const i32x4 bf10 = *(const i32x4*)(Bb + 1 * 2048 + aks0);
    const i32x4 bf11 = *(const i32x4*)(Bb + 1 * 2048 + aks1);
    const i32x4 bf20 = *(const i32x4*)(Bb + 2 * 2048 + aks0);
    const i32x4 bf21 = *(const i32x4*)(Bb + 2 * 2048 + aks1);
    const i32x4 bf30 = *(const i32x4*)(Bb + 3 * 2048 + aks0);
    const i32x4 bf31 = *(const i32x4*)(Bb + 3 * 2048 + aks1);

    // quads 0-1 (A reads inline; scheduler free to interleave)
    {
      AFRAGS(0, pa)
      QUAD(0, pa)
      AFRAGS(1, pb)
      QUAD(1, pb)
    }
    BAR();   // all waves' B-frag (and quad0/1 A) reads retired: B region dead
    if (t + 2 < KT) STAGE_B4(t + 2, p);

    // quads 2-3
    {
      AFRAGS(2, pc)
      QUAD(2, pc)
      AFRAGS(3, pd)
      QUAD(3, pd)
    }

    // end: drain {B(t+1), A(t+1)}; leave B(t+2) in flight
    if (t < KT - 2)       asm volatile("s_waitcnt vmcnt(4)" ::: "memory");
    else if (t == KT - 2) asm volatile("s_waitcnt vmcnt(0)" ::: "memory");
    if (t + 1 < KT) BAR();
  }

  // ---- epilogue: C = sx[row]*sw[col]*acc + bias; NT stores ---------------
  const int crow0 = tm * 256 + wr * 128 + ((lane >> 4) << 2);
  const int ccol0 = tn * 256 + wc * 64 + (lane & 15);
#pragma unroll
  for (int ni = 0; ni < 4; ++ni) {
    const float bv = bias[ccol0 + ni * 16];
    const float swc = sw[ccol0 + ni * 16];
#pragma unroll
    for (int mi = 0; mi < 8; ++mi) {
#pragma unroll
      for (int e = 0; e < 4; ++e) {
        const int row = crow0 + mi * 16 + e;
        __builtin_nontemporal_store(
            sx[row] * swc * (float)acc[mi][ni][e] + bv,
            &C[(size_t)row * N_DIM + ccol0 + ni * 16]);
      }
    }
  }
}

extern "C" void kernel_launch(void* const* d_in, const int* in_sizes, int n_in,
                              void* d_out, int out_size, void* d_ws, size_t ws_size,
                              hipStream_t stream) {
  const float* x    = (const float*)d_in[0];
  const int*   wq   = (const int*)d_in[1];
  const float* wsc  = (const float*)d_in[2];
  const float* bias = (const float*)d_in[3];
  float* out = (float*)d_out;

  const size_t xq_bytes = (size_t)M_DIM * K_DIM;        // 32 MB
  const size_t sx_bytes = (size_t)M_DIM * 4;            // 32 KB
  const size_t w8_bytes = (size_t)N_DIM * K_DIM;        // 64 MB
  const size_t sw_bytes = (size_t)N_DIM * 4;            // 64 KB
  if (ws_size < xq_bytes + sx_bytes + w8_bytes + sw_bytes) return;

  char*  xq  = (char*)d_ws;
  float* sxp = (float*)((char*)d_ws + xq_bytes);
  char*  w8  = (char*)d_ws + xq_bytes + sx_bytes;
  float* swp = (float*)((char*)d_ws + xq_bytes + sx_bytes + w8_bytes);

  quant_x_kernel<<<M_DIM, 256, 0, stream>>>(x, xq, sxp);
  requant_w_kernel<<<N_DIM, 256, 0, stream>>>(wq, wsc, w8, swp);
  gemm_kernel<<<(M_DIM / 256) * (N_DIM / 256), 512, 0, stream>>>(
      xq, w8, swp, sxp, bias, out);
}